// Round 1
// baseline (354.912 us; speedup 1.0000x reference)
//
#include <hip/hip_runtime.h>
#include <hip/hip_bf16.h>
#include <stdint.h>

typedef __attribute__((ext_vector_type(4))) float f32x4;
typedef __attribute__((ext_vector_type(8))) short s16x8;

__device__ __forceinline__ short f2bf(float f) {
  union { float f; uint32_t u; } v; v.f = f;
  uint32_t r = v.u + 0x7FFFu + ((v.u >> 16) & 1u);
  return (short)(r >> 16);
}

__device__ __forceinline__ void async16(const void* g, void* l) {
  __builtin_amdgcn_global_load_lds(
      (const __attribute__((address_space(1))) void*)g,
      (__attribute__((address_space(3))) void*)l, 16, 0, 0);
}

// ---------------- cast x (fp32 -> bf16), 8 elems/thread ----------------
__global__ __launch_bounds__(256) void k_cast_bf16(const float* __restrict__ in,
                                                   short* __restrict__ out, int n8) {
  int i = blockIdx.x * 256 + threadIdx.x;
  if (i >= n8) return;
  const float4* p = (const float4*)in + (size_t)i * 2;
  float4 a = p[0], b = p[1];
  s16x8 o;
  o[0] = f2bf(a.x); o[1] = f2bf(a.y); o[2] = f2bf(a.z); o[3] = f2bf(a.w);
  o[4] = f2bf(b.x); o[5] = f2bf(b.y); o[6] = f2bf(b.z); o[7] = f2bf(b.w);
  ((s16x8*)out)[i] = o;
}

// ---------------- transpose+cast weights: out[n][k] = in[k][n] ----------------
__global__ __launch_bounds__(256) void k_transpose_cast(const float* __restrict__ in,
                                                        short* __restrict__ out,
                                                        int K, int N) {
  int idx = blockIdx.x * 256 + threadIdx.x;
  if (idx >= K * N) return;
  int n = idx / K, k = idx - n * K;
  out[idx] = f2bf(in[(size_t)k * N + n]);
}

// ---------------- m97-style 128x128 bf16 GEMM, A[M][K], B^T[N][K] ----------------
template <bool F32OUT>
__global__ __launch_bounds__(256) void k_gemm_bt(const short* __restrict__ A,
                                                 const short* __restrict__ B,
                                                 const float* __restrict__ bias,
                                                 void* __restrict__ C,
                                                 int M, int N, int K) {
  __shared__ short As[128 * 32];
  __shared__ short Bs[128 * 32];
  const int t = threadIdx.x;
  const int wv = t >> 6, ln = t & 63;
  const int bn = blockIdx.x, bm = blockIdx.y;  // bn fast-varying -> A-panel L2 reuse
  const int rbase = (wv >> 1) * 64, cbase = (wv & 1) * 64;

  f32x4 acc[4][4] = {};

  for (int kt = 0; kt < K; kt += 32) {
#pragma unroll
    for (int p = 0; p < 2; ++p) {
      int c = p * 256 + t;  // 16B chunk id: row = c>>2, k-subcol = c&3
      const short* ga = A + (size_t)(bm * 128 + (c >> 2)) * K + kt + (c & 3) * 8;
      async16(ga, (short*)As + (size_t)(p * 256 + wv * 64) * 8);
      const short* gb = B + (size_t)(bn * 128 + (c >> 2)) * K + kt + (c & 3) * 8;
      async16(gb, (short*)Bs + (size_t)(p * 256 + wv * 64) * 8);
    }
    __syncthreads();
    s16x8 af[4], bf[4];
#pragma unroll
    for (int i = 0; i < 4; ++i)
      af[i] = *(const s16x8*)&As[(rbase + 16 * i + (ln & 15)) * 32 + (ln >> 4) * 8];
#pragma unroll
    for (int j = 0; j < 4; ++j)
      bf[j] = *(const s16x8*)&Bs[(cbase + 16 * j + (ln & 15)) * 32 + (ln >> 4) * 8];
#pragma unroll
    for (int i = 0; i < 4; ++i)
#pragma unroll
      for (int j = 0; j < 4; ++j)
        acc[i][j] = __builtin_amdgcn_mfma_f32_16x16x32_bf16(af[i], bf[j], acc[i][j], 0, 0, 0);
    __syncthreads();
  }

#pragma unroll
  for (int i = 0; i < 4; ++i)
#pragma unroll
    for (int j = 0; j < 4; ++j)
#pragma unroll
      for (int r = 0; r < 4; ++r) {
        int row = bm * 128 + rbase + 16 * i + (ln >> 4) * 4 + r;
        int col = bn * 128 + cbase + 16 * j + (ln & 15);
        float v = acc[i][j][r] + bias[col];
        if (F32OUT)
          ((float*)C)[(size_t)row * N + col] = v;
        else
          ((short*)C)[(size_t)row * N + col] = f2bf(v);
      }
}

// ---------------- fused window attention: 1 wave per (b,h) ----------------
// qkv: [1024*64][1536] bf16 rows (q|k|v each [H=16][d=32] within row)
// writes Y (scrambled per reference transpose) bf16 [65536][512]
__global__ __launch_bounds__(256) void k_attn(const short* __restrict__ qkv,
                                              const float* __restrict__ mask,
                                              const float* __restrict__ bias_table,
                                              short* __restrict__ Y) {
  __shared__ float mask_lds[64 * 64];
  __shared__ float bias_lds[4][128];
  __shared__ short p_lds[4][64][72];  // +8 pad: 2-way bank conflicts only, keeps 16B align

  const int t = threadIdx.x, wv = t >> 6, ln = t & 63;
  const int b = blockIdx.x;
  const int h = blockIdx.y * 4 + wv;

  // stage window mask (shared by all 4 waves: same b)
  const float4* mk = (const float4*)(mask + (size_t)(b & 63) * 4096);
#pragma unroll
  for (int u = 0; u < 4; ++u)
    ((float4*)mask_lds)[t + 256 * u] = mk[t + 256 * u];
  // stage relative-position bias diagonal values for this head
  for (int u = ln; u < 127; u += 64) bias_lds[wv][u] = bias_table[u * 16 + h];
  __syncthreads();

  const short* qb = qkv + (size_t)b * 64 * 1536 + h * 32;

  // ---- QK^T: S = q . k^T  (16 MFMAs, K=32=d) ----
  s16x8 qf[4], kf[4];
#pragma unroll
  for (int i = 0; i < 4; ++i) {
    qf[i] = *(const s16x8*)(qb + (size_t)(16 * i + (ln & 15)) * 1536 + (ln >> 4) * 8);
    kf[i] = *(const s16x8*)(qb + (size_t)(16 * i + (ln & 15)) * 1536 + 512 + (ln >> 4) * 8);
  }
  f32x4 s[4][4] = {};
#pragma unroll
  for (int i = 0; i < 4; ++i)
#pragma unroll
    for (int j = 0; j < 4; ++j)
      s[i][j] = __builtin_amdgcn_mfma_f32_16x16x32_bf16(qf[i], kf[j], s[i][j], 0, 0, 0);

  // ---- scale + bias + mask + softmax (rows in-register, 16-lane reduce) ----
  const float scale = 0.17677669529663687f;  // 32^-0.5
  float rs[16];
#pragma unroll
  for (int i = 0; i < 4; ++i)
#pragma unroll
    for (int r = 0; r < 4; ++r) {
      int nn = 16 * i + (ln >> 4) * 4 + r;
      float vals[4];
      float vmax = -1e30f;
#pragma unroll
      for (int j = 0; j < 4; ++j) {
        int mm = 16 * j + (ln & 15);
        float x = s[i][j][r] * scale + bias_lds[wv][nn - mm + 63] + mask_lds[nn * 64 + mm];
        vals[j] = x;
        vmax = fmaxf(vmax, x);
      }
#pragma unroll
      for (int d = 1; d < 16; d <<= 1) vmax = fmaxf(vmax, __shfl_xor(vmax, d, 64));
      float sum = 0.f;
#pragma unroll
      for (int j = 0; j < 4; ++j) {
        float p = __expf(vals[j] - vmax);
        vals[j] = p;
        sum += p;
      }
#pragma unroll
      for (int d = 1; d < 16; d <<= 1) sum += __shfl_xor(sum, d, 64);
      rs[i * 4 + r] = 1.0f / sum;
#pragma unroll
      for (int j = 0; j < 4; ++j)
        p_lds[wv][nn][16 * j + (ln & 15)] = f2bf(vals[j]);
    }

  // ---- PV: O = P . V  (16 MFMAs, K=64) ----
  const short* vg = qb + 1024;
  f32x4 o[4][2] = {};
#pragma unroll
  for (int kk = 0; kk < 2; ++kk) {
    s16x8 pa[4];
#pragma unroll
    for (int i2 = 0; i2 < 4; ++i2)
      pa[i2] = *(const s16x8*)&p_lds[wv][16 * i2 + (ln & 15)][kk * 32 + (ln >> 4) * 8];
#pragma unroll
    for (int j2 = 0; j2 < 2; ++j2) {
      s16x8 vf;
#pragma unroll
      for (int jj = 0; jj < 8; ++jj)
        vf[jj] = vg[(size_t)(kk * 32 + (ln >> 4) * 8 + jj) * 1536 + 16 * j2 + (ln & 15)];
#pragma unroll
      for (int i2 = 0; i2 < 4; ++i2)
        o[i2][j2] = __builtin_amdgcn_mfma_f32_16x16x32_bf16(pa[i2], vf, o[i2][j2], 0, 0, 0);
    }
  }

  // ---- epilogue: 1/rowsum, scramble-write Y ----
#pragma unroll
  for (int i2 = 0; i2 < 4; ++i2)
#pragma unroll
    for (int j2 = 0; j2 < 2; ++j2)
#pragma unroll
      for (int r = 0; r < 4; ++r) {
        int n = 16 * i2 + (ln >> 4) * 4 + r;
        int d = 16 * j2 + (ln & 15);
        float val = o[i2][j2][r] * rs[i2 * 4 + r];
        int rr = h * 64 + (b >> 4);
        int ss = (b & 15) * 4 + (n >> 4);
        int cc = (n & 15) * 32 + d;
        Y[((size_t)rr * 64 + ss) * 512 + cc] = f2bf(val);
      }
}

extern "C" void kernel_launch(void* const* d_in, const int* in_sizes, int n_in,
                              void* d_out, int out_size, void* d_ws, size_t ws_size,
                              hipStream_t stream) {
  const float* x      = (const float*)d_in[0];
  const float* mask   = (const float*)d_in[1];
  const float* qkv_w  = (const float*)d_in[2];
  const float* qkv_b  = (const float*)d_in[3];
  const float* proj_w = (const float*)d_in[4];
  const float* proj_b = (const float*)d_in[5];
  const float* btab   = (const float*)d_in[6];
  float* out = (float*)d_out;

  char* w = (char*)d_ws;
  short* qkv_ws = (short*)w;                                             // 192 MiB
  short* xbf    = (short*)(w + (size_t)65536 * 1536 * 2);                // 64 MiB
  short* Y      = xbf;                                                   // reuse after GEMM1
  short* wT     = (short*)(w + (size_t)65536 * 1536 * 2 + (size_t)65536 * 512 * 2);
  short* projT  = wT + 1536 * 512;

  k_cast_bf16<<<16384, 256, 0, stream>>>(x, xbf, 33554432 / 8);
  k_transpose_cast<<<(1536 * 512 + 255) / 256, 256, 0, stream>>>(qkv_w, wT, 512, 1536);
  k_transpose_cast<<<(512 * 512 + 255) / 256, 256, 0, stream>>>(proj_w, projT, 512, 512);
  k_gemm_bt<false><<<dim3(12, 512), 256, 0, stream>>>(xbf, wT, qkv_b, qkv_ws, 65536, 1536, 512);
  k_attn<<<dim3(1024, 4), 256, 0, stream>>>(qkv_ws, mask, btab, Y);
  k_gemm_bt<true><<<dim3(4, 512), 256, 0, stream>>>(Y, projT, proj_b, out, 65536, 512, 512);
}

// Round 2
// 307.139 us; speedup vs baseline: 1.1555x; 1.1555x over previous
//
#include <hip/hip_runtime.h>
#include <hip/hip_bf16.h>
#include <stdint.h>

typedef __attribute__((ext_vector_type(4))) float f32x4;
typedef __attribute__((ext_vector_type(8))) short s16x8;

__device__ __forceinline__ short f2bf(float f) {
  union { float f; uint32_t u; } v; v.f = f;
  uint32_t r = v.u + 0x7FFFu + ((v.u >> 16) & 1u);
  return (short)(r >> 16);
}

__device__ __forceinline__ void async16(const void* g, void* l) {
  __builtin_amdgcn_global_load_lds(
      (const __attribute__((address_space(1))) void*)g,
      (__attribute__((address_space(3))) void*)l, 16, 0, 0);
}

// ---------------- cast x (fp32 -> bf16), 8 elems/thread ----------------
__global__ __launch_bounds__(256) void k_cast_bf16(const float* __restrict__ in,
                                                   short* __restrict__ out, int n8) {
  int i = blockIdx.x * 256 + threadIdx.x;
  if (i >= n8) return;
  const float4* p = (const float4*)in + (size_t)i * 2;
  float4 a = p[0], b = p[1];
  s16x8 o;
  o[0] = f2bf(a.x); o[1] = f2bf(a.y); o[2] = f2bf(a.z); o[3] = f2bf(a.w);
  o[4] = f2bf(b.x); o[5] = f2bf(b.y); o[6] = f2bf(b.z); o[7] = f2bf(b.w);
  ((s16x8*)out)[i] = o;
}

// ---------------- transpose+cast weights: out[n][k] = in[k][n] ----------------
__global__ __launch_bounds__(256) void k_transpose_cast(const float* __restrict__ in,
                                                        short* __restrict__ out,
                                                        int K, int N) {
  int idx = blockIdx.x * 256 + threadIdx.x;
  if (idx >= K * N) return;
  int n = idx / K, k = idx - n * K;
  out[idx] = f2bf(in[(size_t)k * N + n]);
}

// ================= 256x256 8-phase bf16 GEMM (T2+T3+T4+T5) =================
// A [M][K] bf16, B^T [N][K] bf16, C [M][N]. BK=64, 8 waves (2Mx4N), 512 thr.
// LDS 128 KiB: 2 bufs x (A 256x64 + B 256x64) bf16. Swizzle: 16B-slot index
// XOR (row&7), applied on the GLOBAL source (global_load_lds writes linear)
// and on the ds_read address.
// Schedule per K-tile T (4 phases, 2 barriers each):
//   ph0: read bf[4][2] + af[0..1][2]; issue A0(T+1)
//   ph1: read af[2..3][2];            issue A1(T+1)
//   ph2: read af[4..5][2];            issue B0(T+2)  (into read buf: B reads
//   ph3: read af[6..7][2];            issue B1(T+2)   were all in ph0 -> safe)
//   tail of ph3: vmcnt(4)  (allow 2 newest half-tiles in flight)
#define TILE_SH 16384  // 256*64 shorts per matrix tile

template <bool F32OUT>
__global__ __launch_bounds__(512, 2) void k_gemm256(const short* __restrict__ A,
                                                    const short* __restrict__ Bw,
                                                    const float* __restrict__ bias,
                                                    void* __restrict__ C,
                                                    int M, int N, int K, int nbn) {
  __shared__ short lds[2 * 2 * TILE_SH];  // 128 KiB
  const int t = threadIdx.x;
  const int w = t >> 6, l = t & 63;
  const int wm = w >> 2, wn = w & 3;

  // bijective XCD swizzle (gridDim.x % 8 == 0 for both our GEMMs)
  const int nwg = gridDim.x;
  const int cpx = nwg >> 3;
  const int wg = ((int)blockIdx.x & 7) * cpx + ((int)blockIdx.x >> 3);
  const int bn = wg % nbn, bm = wg / nbn;

  const int NT = K >> 6;  // assumed >= 3

  auto stage = [&](const short* __restrict__ G, int row0, int kt, short* dst) {
#pragma unroll
    for (int L = 0; L < 2; ++L) {
      int cw = L * 512 + (t & ~63);  // wave-uniform chunk base
      int c = cw + l;
      int r = c >> 3, s = c & 7;
      async16(G + (size_t)(row0 + r) * K + kt + ((s ^ (r & 7)) << 3), dst + cw * 8);
    }
  };
  auto issueA = [&](int Tt, int hf) {
    stage(A, bm * 256 + hf * 128, Tt * 64, lds + (Tt & 1) * 32768 + hf * 8192);
  };
  auto issueB = [&](int Tt, int hf) {
    stage(Bw, bn * 256 + hf * 128, Tt * 64, lds + (Tt & 1) * 32768 + TILE_SH + hf * 8192);
  };

  // per-lane swizzled ds_read offsets (shorts)
  const int g = l >> 4, v = l & 7;
  int ofsA[2], ofsB[2];
#pragma unroll
  for (int ks = 0; ks < 2; ++ks) {
    ofsA[ks] = (wm * 128 + (l & 15)) * 64 + (((ks * 4 + g) ^ v) << 3);
    ofsB[ks] = (wn * 64 + (l & 15)) * 64 + (((ks * 4 + g) ^ v) << 3);
  }

  f32x4 acc[8][4] = {};
  s16x8 bfr[4][2];

  // prologue: B0(0) B1(0) A0(0) A1(0) B0(1) B1(1) -> 12 loads
  issueB(0, 0); issueB(0, 1); issueA(0, 0); issueA(0, 1);
  if (NT > 1) { issueB(1, 0); issueB(1, 1); }
  asm volatile("s_waitcnt vmcnt(4)" ::: "memory");
  __builtin_amdgcn_s_barrier();

#define PHASE(AI0, STAGE_STMT, TAIL_STMT)                                                                      \
  {                                                                                                            \
    s16x8 a00 = *(const s16x8*)(Ab + ofsA[0] + (AI0) * 1024);                                                  \
    s16x8 a01 = *(const s16x8*)(Ab + ofsA[1] + (AI0) * 1024);                                                  \
    s16x8 a10 = *(const s16x8*)(Ab + ofsA[0] + ((AI0) + 1) * 1024);                                            \
    s16x8 a11 = *(const s16x8*)(Ab + ofsA[1] + ((AI0) + 1) * 1024);                                            \
    STAGE_STMT;                                                                                                \
    __builtin_amdgcn_s_barrier();                                                                              \
    asm volatile("s_waitcnt lgkmcnt(0)" ::: "memory");                                                         \
    __builtin_amdgcn_s_setprio(1);                                                                             \
    _Pragma("unroll")                                                                                          \
    for (int nj = 0; nj < 4; ++nj) {                                                                           \
      acc[(AI0)][nj] = __builtin_amdgcn_mfma_f32_16x16x32_bf16(a00, bfr[nj][0], acc[(AI0)][nj], 0, 0, 0);      \
      acc[(AI0)][nj] = __builtin_amdgcn_mfma_f32_16x16x32_bf16(a01, bfr[nj][1], acc[(AI0)][nj], 0, 0, 0);      \
      acc[(AI0) + 1][nj] = __builtin_amdgcn_mfma_f32_16x16x32_bf16(a10, bfr[nj][0], acc[(AI0) + 1][nj], 0, 0, 0); \
      acc[(AI0) + 1][nj] = __builtin_amdgcn_mfma_f32_16x16x32_bf16(a11, bfr[nj][1], acc[(AI0) + 1][nj], 0, 0, 0); \
    }                                                                                                          \
    __builtin_amdgcn_s_setprio(0);                                                                             \
    TAIL_STMT;                                                                                                 \
    __builtin_amdgcn_s_barrier();                                                                              \
  }

  for (int T = 0; T < NT; ++T) {
    const short* Ab = lds + (T & 1) * 32768;
    const short* Bb = Ab + TILE_SH;
#pragma unroll
    for (int nj = 0; nj < 4; ++nj)
#pragma unroll
      for (int ks = 0; ks < 2; ++ks)
        bfr[nj][ks] = *(const s16x8*)(Bb + ofsB[ks] + nj * 1024);

    PHASE(0, if (T + 1 < NT) issueA(T + 1, 0), );
    PHASE(2, if (T + 1 < NT) issueA(T + 1, 1), );
    PHASE(4, if (T + 2 < NT) issueB(T + 2, 0), );
    PHASE(6, if (T + 2 < NT) issueB(T + 2, 1),
          if (T + 2 < NT) { asm volatile("s_waitcnt vmcnt(4)" ::: "memory"); }
          else if (T + 1 < NT) { asm volatile("s_waitcnt vmcnt(0)" ::: "memory"); });
  }
#undef PHASE

  // epilogue
#pragma unroll
  for (int ai = 0; ai < 8; ++ai)
#pragma unroll
    for (int nj = 0; nj < 4; ++nj) {
      int col = bn * 256 + wn * 64 + nj * 16 + (l & 15);
      float bv = bias[col];
#pragma unroll
      for (int r = 0; r < 4; ++r) {
        int row = bm * 256 + wm * 128 + ai * 16 + (l >> 4) * 4 + r;
        float vv = acc[ai][nj][r] + bv;
        if (F32OUT)
          ((float*)C)[(size_t)row * N + col] = vv;
        else
          ((short*)C)[(size_t)row * N + col] = f2bf(vv);
      }
    }
}

// ---------------- fused window attention: 1 wave per (b,h) ----------------
__global__ __launch_bounds__(256) void k_attn(const short* __restrict__ qkv,
                                              const float* __restrict__ mask,
                                              const float* __restrict__ bias_table,
                                              short* __restrict__ Y) {
  __shared__ float mask_lds[64 * 64];
  __shared__ float bias_lds[4][128];
  __shared__ short p_lds[4][64][72];

  const int t = threadIdx.x, wv = t >> 6, ln = t & 63;
  const int b = blockIdx.x;
  const int h = blockIdx.y * 4 + wv;

  const float4* mk = (const float4*)(mask + (size_t)(b & 63) * 4096);
#pragma unroll
  for (int u = 0; u < 4; ++u)
    ((float4*)mask_lds)[t + 256 * u] = mk[t + 256 * u];
  for (int u = ln; u < 127; u += 64) bias_lds[wv][u] = bias_table[u * 16 + h];
  __syncthreads();

  const short* qb = qkv + (size_t)b * 64 * 1536 + h * 32;

  s16x8 qf[4], kf[4];
#pragma unroll
  for (int i = 0; i < 4; ++i) {
    qf[i] = *(const s16x8*)(qb + (size_t)(16 * i + (ln & 15)) * 1536 + (ln >> 4) * 8);
    kf[i] = *(const s16x8*)(qb + (size_t)(16 * i + (ln & 15)) * 1536 + 512 + (ln >> 4) * 8);
  }
  f32x4 s[4][4] = {};
#pragma unroll
  for (int i = 0; i < 4; ++i)
#pragma unroll
    for (int j = 0; j < 4; ++j)
      s[i][j] = __builtin_amdgcn_mfma_f32_16x16x32_bf16(qf[i], kf[j], s[i][j], 0, 0, 0);

  const float scale = 0.17677669529663687f;
  float rs[16];
#pragma unroll
  for (int i = 0; i < 4; ++i)
#pragma unroll
    for (int r = 0; r < 4; ++r) {
      int nn = 16 * i + (ln >> 4) * 4 + r;
      float vals[4];
      float vmax = -1e30f;
#pragma unroll
      for (int j = 0; j < 4; ++j) {
        int mm = 16 * j + (ln & 15);
        float x = s[i][j][r] * scale + bias_lds[wv][nn - mm + 63] + mask_lds[nn * 64 + mm];
        vals[j] = x;
        vmax = fmaxf(vmax, x);
      }
#pragma unroll
      for (int d = 1; d < 16; d <<= 1) vmax = fmaxf(vmax, __shfl_xor(vmax, d, 64));
      float sum = 0.f;
#pragma unroll
      for (int j = 0; j < 4; ++j) {
        float p = __expf(vals[j] - vmax);
        vals[j] = p;
        sum += p;
      }
#pragma unroll
      for (int d = 1; d < 16; d <<= 1) sum += __shfl_xor(sum, d, 64);
      rs[i * 4 + r] = 1.0f / sum;
#pragma unroll
      for (int j = 0; j < 4; ++j)
        p_lds[wv][nn][16 * j + (ln & 15)] = f2bf(vals[j]);
    }

  const short* vg = qb + 1024;
  f32x4 o[4][2] = {};
#pragma unroll
  for (int kk = 0; kk < 2; ++kk) {
    s16x8 pa[4];
#pragma unroll
    for (int i2 = 0; i2 < 4; ++i2)
      pa[i2] = *(const s16x8*)&p_lds[wv][16 * i2 + (ln & 15)][kk * 32 + (ln >> 4) * 8];
#pragma unroll
    for (int j2 = 0; j2 < 2; ++j2) {
      s16x8 vf;
#pragma unroll
      for (int jj = 0; jj < 8; ++jj)
        vf[jj] = vg[(size_t)(kk * 32 + (ln >> 4) * 8 + jj) * 1536 + 16 * j2 + (ln & 15)];
#pragma unroll
      for (int i2 = 0; i2 < 4; ++i2)
        o[i2][j2] = __builtin_amdgcn_mfma_f32_16x16x32_bf16(pa[i2], vf, o[i2][j2], 0, 0, 0);
    }
  }

#pragma unroll
  for (int i2 = 0; i2 < 4; ++i2)
#pragma unroll
    for (int j2 = 0; j2 < 2; ++j2)
#pragma unroll
      for (int r = 0; r < 4; ++r) {
        int n = 16 * i2 + (ln >> 4) * 4 + r;
        int d = 16 * j2 + (ln & 15);
        float val = o[i2][j2][r] * rs[i2 * 4 + r];
        int rr = h * 64 + (b >> 4);
        int ss = (b & 15) * 4 + (n >> 4);
        int cc = (n & 15) * 32 + d;
        Y[((size_t)rr * 64 + ss) * 512 + cc] = f2bf(val);
      }
}

extern "C" void kernel_launch(void* const* d_in, const int* in_sizes, int n_in,
                              void* d_out, int out_size, void* d_ws, size_t ws_size,
                              hipStream_t stream) {
  const float* x      = (const float*)d_in[0];
  const float* mask   = (const float*)d_in[1];
  const float* qkv_w  = (const float*)d_in[2];
  const float* qkv_b  = (const float*)d_in[3];
  const float* proj_w = (const float*)d_in[4];
  const float* proj_b = (const float*)d_in[5];
  const float* btab   = (const float*)d_in[6];
  float* out = (float*)d_out;

  char* w = (char*)d_ws;
  short* qkv_ws = (short*)w;                                             // 192 MiB
  short* xbf    = (short*)(w + (size_t)65536 * 1536 * 2);                // 64 MiB
  short* Y      = xbf;                                                   // reuse after GEMM1
  short* wT     = (short*)(w + (size_t)65536 * 1536 * 2 + (size_t)65536 * 512 * 2);
  short* projT  = wT + 1536 * 512;

  k_cast_bf16<<<16384, 256, 0, stream>>>(x, xbf, 33554432 / 8);
  k_transpose_cast<<<(1536 * 512 + 255) / 256, 256, 0, stream>>>(qkv_w, wT, 512, 1536);
  k_transpose_cast<<<(512 * 512 + 255) / 256, 256, 0, stream>>>(proj_w, projT, 512, 512);
  k_gemm256<false><<<1536, 512, 0, stream>>>(xbf, wT, qkv_b, qkv_ws, 65536, 1536, 512, 6);
  k_attn<<<dim3(1024, 4), 256, 0, stream>>>(qkv_ws, mask, btab, Y);
  k_gemm256<true><<<512, 512, 0, stream>>>(Y, projT, proj_b, out, 65536, 512, 512, 2);
}